// Round 5
// baseline (737.756 us; speedup 1.0000x reference)
//
#include <hip/hip_runtime.h>
#include <hip/hip_bf16.h>

#define NROWS 8192
#define DEMB 256
#define MARGIN 0.2f
#define NCLS 512
#define TPC 8                    // B tiles (128 cols) per chunk
#define NSTEP 16                 // 8 tiles * 2 half-K steps (BK=128)
#define PCAP 131072              // pair-record capacity (expected ~65k)

typedef __attribute__((ext_vector_type(4))) float f32x4;
typedef __attribute__((ext_vector_type(8))) short bf16x8;

static __device__ __forceinline__ unsigned short f2b(float f) {
    unsigned u = __builtin_bit_cast(unsigned, f);
    u += 0x7fffu + ((u >> 16) & 1u);           // RNE round to bf16
    return (unsigned short)(u >> 16);
}
static __device__ __forceinline__ float b2f(unsigned short b) {
    unsigned u = ((unsigned)b) << 16;
    return __builtin_bit_cast(float, u);
}
// order-preserving f32 -> u32 encode (max-compatible; finite values never encode to 0)
static __device__ __forceinline__ unsigned encf(float f) {
    unsigned u = __builtin_bit_cast(unsigned, f);
    return (u & 0x80000000u) ? ~u : (u | 0x80000000u);
}
static __device__ __forceinline__ float decf(unsigned e) {
    unsigned u = (e & 0x80000000u) ? (e ^ 0x80000000u) : ~e;
    return __builtin_bit_cast(float, u);
}
static __device__ __forceinline__ void gload16(const void* g, void* l) {
    __builtin_amdgcn_global_load_lds(
        (const __attribute__((address_space(1))) unsigned int*)g,
        (__attribute__((address_space(3))) unsigned int*)l, 16, 0, 0);
}

// K1: row-L2-normalize fp32 -> bf16; also zero amax + pair counter.
__global__ __launch_bounds__(256) void k_norm(const float* __restrict__ x,
                                              unsigned short* __restrict__ xnb,
                                              unsigned* __restrict__ amax,
                                              unsigned* __restrict__ pcnt) {
    int gid = blockIdx.x * blockDim.x + threadIdx.x;
    if (gid < NROWS) amax[gid] = 0u;
    if (gid == 0) *pcnt = 0u;
    int row  = gid >> 6;
    int lane = threadIdx.x & 63;
    const float4* p = reinterpret_cast<const float4*>(x + (size_t)row * DEMB) + lane;
    float4 v = *p;
    float s = v.x * v.x + v.y * v.y + v.z * v.z + v.w * v.w;
#pragma unroll
    for (int m = 1; m < 64; m <<= 1) s += __shfl_xor(s, m);
    float inv = 1.0f / fmaxf(sqrtf(s), 1e-8f);
    ushort4 o;
    o.x = f2b(v.x * inv); o.y = f2b(v.y * inv);
    o.z = f2b(v.z * inv); o.w = f2b(v.w * inv);
    *(reinterpret_cast<ushort4*>(xnb + (size_t)row * DEMB) + lane) = o;
}

// K2: strip-streaming MFMA row-max + positive-pair extraction.
// Grid (64 strips, 8 chunks), 512 threads. A-strip in registers; B streamed
// via 16-step dbuf LDS pipeline (XOR-swizzled). Per-tile fold: label-masked
// row-max into registers; same-label upper-tri hits appended as {row,dot}.
__global__ __launch_bounds__(512, 2) void k_maxneg(const unsigned short* __restrict__ xnb,
                                                   const int* __restrict__ labels,
                                                   unsigned* __restrict__ amax,
                                                   unsigned* __restrict__ pcnt,
                                                   uint2* __restrict__ prec) {
    extern __shared__ char lds[];
    unsigned short* Bl = (unsigned short*)lds;   // dbuf: 2 x 32KB

    int tid  = threadIdx.x;
    int wid  = tid >> 6, lane = tid & 63;
    int wr   = wid >> 1, wc = wid & 1;           // 4 row-subwaves x 2 col-subwaves
    int arow = lane & 15, kgrp = lane >> 4;
    int sw   = arow << 4;

    int i0 = blockIdx.x * 128;
    int j0 = blockIdx.y * (TPC * 128);

    // Hoist A fragments: row = i0 + wr*32 + m*16 + arow, k = kk*32 + kgrp*8
    bf16x8 a[2][8];
    const unsigned short* ap0 = xnb + (size_t)(i0 + wr * 32 + arow) * DEMB + kgrp * 8;
#pragma unroll
    for (int m = 0; m < 2; ++m)
#pragma unroll
        for (int kk = 0; kk < 8; ++kk)
            a[m][kk] = *(const bf16x8*)(ap0 + m * 16 * DEMB + kk * 32);

    int rlab[2][4];
#pragma unroll
    for (int m = 0; m < 2; ++m)
#pragma unroll
        for (int r = 0; r < 4; ++r)
            rlab[m][r] = labels[i0 + wr * 32 + m * 16 + kgrp * 4 + r];

    // static swizzled ds_read addresses: rcb[k] = rowbase(n=0) + swizzled col
    int rcb[4];
#pragma unroll
    for (int k2 = 0; k2 < 4; ++k2)
        rcb[k2] = (wc * 64 + arow) * 256 + ((k2 * 64 + kgrp * 16) ^ sw);

    float rmax[2][4] = {{-1e30f, -1e30f, -1e30f, -1e30f},
                        {-1e30f, -1e30f, -1e30f, -1e30f}};
    f32x4 acc[2][4] = {};

    // stage B half-tile: tile t, k-half h -> 128 rows x 128 k-cols = 32KB
    auto stage = [&](int buf, int t, int h) {
#pragma unroll
        for (int is = 0; is < 4; ++is) {
            int idx  = is * 512 + tid;                  // 16B chunk id 0..2047
            int row  = idx >> 4;                        // 16 chunks per 256B row
            int colb = (idx & 15) << 4;
            int scol = (colb ^ ((row & 15) << 4)) >> 1; // pre-swizzled elem col
            const unsigned short* src =
                xnb + (size_t)(j0 + t * 128 + row) * DEMB + h * 128 + scol;
            unsigned short* dst = Bl + buf * 16384 + is * 4096 + wid * 512;
            gload16(src, dst);
        }
    };

    int clab[4], nlab[4];
    stage(0, 0, 0);
#pragma unroll
    for (int n = 0; n < 4; ++n) clab[n] = labels[j0 + wc * 64 + n * 16 + arow];

    int cb = j0 + wc * 64;                               // column base of current tile
    const char* BlC = (const char*)Bl;

    for (int s = 0; s < NSTEP; ++s) {
        __syncthreads();                                 // buf[s&1] ready
        if (s + 1 < NSTEP) stage((s + 1) & 1, (s + 1) >> 1, (s + 1) & 1);
        int t = s >> 1, h = s & 1;
        if (h == 0 && t + 1 < TPC) {
#pragma unroll
            for (int n = 0; n < 4; ++n)
                nlab[n] = labels[j0 + (t + 1) * 128 + wc * 64 + n * 16 + arow];
        }
        bf16x8 b[4][4];
        if (s & 1) {
#pragma unroll
            for (int n = 0; n < 4; ++n)
#pragma unroll
                for (int k2 = 0; k2 < 4; ++k2)
                    b[n][k2] = *(const bf16x8*)(BlC + 32768 + n * 4096 + rcb[k2]);
        } else {
#pragma unroll
            for (int n = 0; n < 4; ++n)
#pragma unroll
                for (int k2 = 0; k2 < 4; ++k2)
                    b[n][k2] = *(const bf16x8*)(BlC + n * 4096 + rcb[k2]);
        }
        __builtin_amdgcn_s_setprio(1);
#pragma unroll
        for (int m = 0; m < 2; ++m)
#pragma unroll
            for (int n = 0; n < 4; ++n)
#pragma unroll
                for (int k2 = 0; k2 < 4; ++k2)
                    acc[m][n] = __builtin_amdgcn_mfma_f32_16x16x32_bf16(
                        a[m][h * 4 + k2], b[n][k2], acc[m][n], 0, 0, 0);
        __builtin_amdgcn_s_setprio(0);

        if (h == 1) {                                    // tile done: masked fold + extract
#pragma unroll
            for (int m = 0; m < 2; ++m)
#pragma unroll
                for (int r = 0; r < 4; ++r) {
                    int rl = rlab[m][r];
                    float v = rmax[m][r];
                    int hb = 0;
#pragma unroll
                    for (int n = 0; n < 4; ++n) {
                        if (clab[n] != rl) v = fmaxf(v, acc[m][n][r]);
                        else hb |= 1 << n;
                    }
                    rmax[m][r] = v;
                    if (hb) {                            // rare: same-label hit(s)
                        int grow_ = i0 + wr * 32 + m * 16 + kgrp * 4 + r;
#pragma unroll
                        for (int n = 0; n < 4; ++n)
                            if ((hb >> n) & 1) {
                                int gcol = cb + n * 16 + arow;
                                if (gcol > grow_) {
                                    unsigned slot = atomicAdd(pcnt, 1u);
                                    if (slot < PCAP)
                                        prec[slot] = make_uint2(
                                            (unsigned)grow_,
                                            __builtin_bit_cast(unsigned, acc[m][n][r]));
                                }
                            }
                    }
                }
#pragma unroll
            for (int m = 0; m < 2; ++m)
#pragma unroll
                for (int n = 0; n < 4; ++n) acc[m][n] = (f32x4){0.f, 0.f, 0.f, 0.f};
#pragma unroll
            for (int n = 0; n < 4; ++n) clab[n] = nlab[n];
            cb += 128;
        }
    }

    // Reduce over 16 col-lanes, combine wc pair via LDS, one atomic per row.
    float* smax = (float*)Bl;                            // [2][128] in buf0 (dead)
#pragma unroll
    for (int m = 0; m < 2; ++m)
#pragma unroll
        for (int r = 0; r < 4; ++r) {
            float v = rmax[m][r];
#pragma unroll
            for (int msk = 1; msk < 16; msk <<= 1) v = fmaxf(v, __shfl_xor(v, msk));
            if (arow == 0) smax[wc * 128 + wr * 32 + m * 16 + kgrp * 4 + r] = v;
        }
    __syncthreads();
    if (tid < 128) {
        float v = fmaxf(smax[tid], smax[128 + tid]);
        if (v > -1e29f) atomicMax(amax + i0 + tid, encf(v));
    }
}

// K3: finalize pair records: loss = relu(1 - dot - dmin[row] + margin)
__global__ __launch_bounds__(256) void k_pairfin(const uint2* __restrict__ prec,
                                                 const unsigned* __restrict__ pcnt,
                                                 const unsigned* __restrict__ amax,
                                                 float* __restrict__ pbl,
                                                 int* __restrict__ pbc) {
    __shared__ float sl[256];
    __shared__ int   sc[256];
    unsigned nrec = *pcnt;
    if (nrec > PCAP) nrec = PCAP;
    int tid = threadIdx.x;
    float ls = 0.f;
    int cn = 0;
    for (unsigned i = blockIdx.x * 256 + tid; i < nrec; i += 64 * 256) {
        uint2 rec = prec[i];
        unsigned e = amax[rec.x];
        if (e != 0u) {                                   // has_neg(anchor)
            float dmin = 1.0f - decf(e);
            float dot  = __builtin_bit_cast(float, rec.y);
            ls += fmaxf(1.0f - dot - dmin + MARGIN, 0.0f);
            cn += 1;
        }
    }
    sl[tid] = ls; sc[tid] = cn;
    __syncthreads();
    for (int st = 128; st > 0; st >>= 1) {
        if (tid < st) { sl[tid] += sl[tid + st]; sc[tid] += sc[tid + st]; }
        __syncthreads();
    }
    if (tid == 0) { pbl[blockIdx.x] = sl[0]; pbc[blockIdx.x] = sc[0]; }
}

// K4: final reduce over 64 partials -> out[0]=loss, out[1]=count
__global__ __launch_bounds__(64) void k_final(const float* __restrict__ pbl,
                                              const int* __restrict__ pbc,
                                              float* __restrict__ out) {
    int lane = threadIdx.x;
    float s = pbl[lane];
    int   c = pbc[lane];
#pragma unroll
    for (int m = 1; m < 64; m <<= 1) {
        s += __shfl_xor(s, m);
        c += __shfl_xor(c, m);
    }
    if (lane == 0) {
        out[0] = (c > 0) ? s / (float)c : 0.0f;
        out[1] = (float)c;
    }
}

extern "C" void kernel_launch(void* const* d_in, const int* in_sizes, int n_in,
                              void* d_out, int out_size, void* d_ws, size_t ws_size,
                              hipStream_t stream) {
    const float* emb  = (const float*)d_in[0];
    const int* labels = (const int*)d_in[1];
    float* out = (float*)d_out;

    char* ws = (char*)d_ws;
    unsigned short* xnb = (unsigned short*)ws;                            // 4 MB
    unsigned* amax = (unsigned*)(ws + (size_t)4 * 1024 * 1024);           // 32 KB
    unsigned* pcnt = (unsigned*)(ws + (size_t)4 * 1024 * 1024 + 32768);   // 4 B (padded)
    float*    pbl  = (float*)   (ws + (size_t)4 * 1024 * 1024 + 33024);   // 256 B
    int*      pbc  = (int*)     (ws + (size_t)4 * 1024 * 1024 + 33280);   // 256 B
    uint2*    prec = (uint2*)   (ws + (size_t)4 * 1024 * 1024 + 33792);   // 1 MB

    k_norm<<<NROWS / 4, 256, 0, stream>>>(emb, xnb, amax, pcnt);
    dim3 g2(NROWS / 128, NCLS / 64);   // 64 strips x 8 chunks
    k_maxneg<<<g2, 512, 65536, stream>>>(xnb, labels, amax, pcnt, prec);
    k_pairfin<<<64, 256, 0, stream>>>(prec, pcnt, amax, pbl, pbc);
    k_final<<<1, 64, 0, stream>>>(pbl, pbc, out);
}

// Round 6
// 730.819 us; speedup vs baseline: 1.0095x; 1.0095x over previous
//
#include <hip/hip_runtime.h>
#include <hip/hip_bf16.h>

#define NROWS 8192
#define DEMB 256
#define MARGIN 0.2f
#define NCLS 512
#define TPC 8                    // B tiles (128 cols) per chunk
#define PCAP 131072              // pair-record capacity (expected ~65k)

typedef __attribute__((ext_vector_type(4))) float f32x4;
typedef __attribute__((ext_vector_type(8))) short bf16x8;

static __device__ __forceinline__ unsigned short f2b(float f) {
    unsigned u = __builtin_bit_cast(unsigned, f);
    u += 0x7fffu + ((u >> 16) & 1u);           // RNE round to bf16
    return (unsigned short)(u >> 16);
}
static __device__ __forceinline__ float b2f(unsigned short b) {
    unsigned u = ((unsigned)b) << 16;
    return __builtin_bit_cast(float, u);
}
// order-preserving f32 -> u32 encode (max-compatible; finite values never encode to 0)
static __device__ __forceinline__ unsigned encf(float f) {
    unsigned u = __builtin_bit_cast(unsigned, f);
    return (u & 0x80000000u) ? ~u : (u | 0x80000000u);
}
static __device__ __forceinline__ float decf(unsigned e) {
    unsigned u = (e & 0x80000000u) ? (e ^ 0x80000000u) : ~e;
    return __builtin_bit_cast(float, u);
}
static __device__ __forceinline__ void gload16(const void* g, void* l) {
    __builtin_amdgcn_global_load_lds(
        (const __attribute__((address_space(1))) unsigned int*)g,
        (__attribute__((address_space(3))) unsigned int*)l, 16, 0, 0);
}

// K1: row-L2-normalize fp32 -> bf16; also zero amax + pair counter.
__global__ __launch_bounds__(256) void k_norm(const float* __restrict__ x,
                                              unsigned short* __restrict__ xnb,
                                              unsigned* __restrict__ amax,
                                              unsigned* __restrict__ pcnt) {
    int gid = blockIdx.x * blockDim.x + threadIdx.x;
    if (gid < NROWS) amax[gid] = 0u;
    if (gid == 0) *pcnt = 0u;
    int row  = gid >> 6;
    int lane = threadIdx.x & 63;
    const float4* p = reinterpret_cast<const float4*>(x + (size_t)row * DEMB) + lane;
    float4 v = *p;
    float s = v.x * v.x + v.y * v.y + v.z * v.z + v.w * v.w;
#pragma unroll
    for (int m = 1; m < 64; m <<= 1) s += __shfl_xor(s, m);
    float inv = 1.0f / fmaxf(sqrtf(s), 1e-8f);
    ushort4 o;
    o.x = f2b(v.x * inv); o.y = f2b(v.y * inv);
    o.z = f2b(v.z * inv); o.w = f2b(v.w * inv);
    *(reinterpret_cast<ushort4*>(xnb + (size_t)row * DEMB) + lane) = o;
}

// K2: strip-streaming MFMA row-max + positive-pair extraction.
// Grid (64 strips, 8 chunks), 512 threads. A-strip in registers; B streamed
// via dbuf LDS pipeline, 2 explicit half-K steps per tile (ALL indices
// compile-time -> no scratch). XOR-swizzled LDS. Per-tile fold: label-masked
// row-max into registers; same-label upper-tri hits appended as {row,dot}.
__global__ __launch_bounds__(512, 2) void k_maxneg(const unsigned short* __restrict__ xnb,
                                                   const int* __restrict__ labels,
                                                   unsigned* __restrict__ amax,
                                                   unsigned* __restrict__ pcnt,
                                                   uint2* __restrict__ prec) {
    extern __shared__ char lds[];
    unsigned short* Bl = (unsigned short*)lds;   // dbuf: 2 x 32KB
    const char* BlC = (const char*)Bl;

    int tid  = threadIdx.x;
    int wid  = tid >> 6, lane = tid & 63;
    int wr   = wid >> 1, wc = wid & 1;           // 4 row-subwaves x 2 col-subwaves
    int arow = lane & 15, kgrp = lane >> 4;
    int sw   = arow << 4;

    int i0 = blockIdx.x * 128;
    int j0 = blockIdx.y * (TPC * 128);

    // Hoist A fragments: row = i0 + wr*32 + m*16 + arow, k = kk*32 + kgrp*8
    bf16x8 a[2][8];
    const unsigned short* ap0 = xnb + (size_t)(i0 + wr * 32 + arow) * DEMB + kgrp * 8;
#pragma unroll
    for (int m = 0; m < 2; ++m)
#pragma unroll
        for (int kk = 0; kk < 8; ++kk)
            a[m][kk] = *(const bf16x8*)(ap0 + m * 16 * DEMB + kk * 32);

    int rlab[2][4];
#pragma unroll
    for (int m = 0; m < 2; ++m)
#pragma unroll
        for (int r = 0; r < 4; ++r)
            rlab[m][r] = labels[i0 + wr * 32 + m * 16 + kgrp * 4 + r];

    // static swizzled ds_read offsets (n-stride 4096 added as literal)
    int rcb[4];
#pragma unroll
    for (int k2 = 0; k2 < 4; ++k2)
        rcb[k2] = (wc * 64 + arow) * 256 + ((k2 * 64 + kgrp * 16) ^ sw);

    float rmax[2][4] = {{-1e30f, -1e30f, -1e30f, -1e30f},
                        {-1e30f, -1e30f, -1e30f, -1e30f}};
    f32x4 acc[2][4] = {};

    // stage B half-tile: tile t, k-half h -> 128 rows x 128 k-cols = 32KB
    auto stage = [&](int buf, int t, int h) {
#pragma unroll
        for (int is = 0; is < 4; ++is) {
            int idx  = is * 512 + tid;                  // 16B chunk id 0..2047
            int row  = idx >> 4;                        // 16 chunks per 256B row
            int colb = (idx & 15) << 4;
            int scol = (colb ^ ((row & 15) << 4)) >> 1; // pre-swizzled elem col
            const unsigned short* src =
                xnb + (size_t)(j0 + t * 128 + row) * DEMB + h * 128 + scol;
            unsigned short* dst = Bl + buf * 16384 + is * 4096 + wid * 512;
            gload16(src, dst);
        }
    };

    int clab[4], nlab[4];
    stage(0, 0, 0);
#pragma unroll
    for (int n = 0; n < 4; ++n) clab[n] = labels[j0 + wc * 64 + n * 16 + arow];

    int cb = j0 + wc * 64;                               // column base of current tile

    for (int t = 0; t < TPC; ++t) {
        // ---- half 0: compute from buf0, prefetch half1 -> buf1 ----
        __syncthreads();                                 // buf0 ready
        stage(1, t, 1);
        if (t + 1 < TPC) {
#pragma unroll
            for (int n = 0; n < 4; ++n)
                nlab[n] = labels[j0 + (t + 1) * 128 + wc * 64 + n * 16 + arow];
        }
        {
            bf16x8 b[4][4];
#pragma unroll
            for (int n = 0; n < 4; ++n)
#pragma unroll
                for (int k2 = 0; k2 < 4; ++k2)
                    b[n][k2] = *(const bf16x8*)(BlC + n * 4096 + rcb[k2]);
            __builtin_amdgcn_s_setprio(1);
#pragma unroll
            for (int m = 0; m < 2; ++m)
#pragma unroll
                for (int n = 0; n < 4; ++n)
#pragma unroll
                    for (int k2 = 0; k2 < 4; ++k2)
                        acc[m][n] = __builtin_amdgcn_mfma_f32_16x16x32_bf16(
                            a[m][k2], b[n][k2], acc[m][n], 0, 0, 0);
            __builtin_amdgcn_s_setprio(0);
        }
        // ---- half 1: compute from buf1, prefetch next tile half0 -> buf0 ----
        __syncthreads();                                 // buf1 ready
        if (t + 1 < TPC) stage(0, t + 1, 0);
        {
            bf16x8 b[4][4];
#pragma unroll
            for (int n = 0; n < 4; ++n)
#pragma unroll
                for (int k2 = 0; k2 < 4; ++k2)
                    b[n][k2] = *(const bf16x8*)(BlC + 32768 + n * 4096 + rcb[k2]);
            __builtin_amdgcn_s_setprio(1);
#pragma unroll
            for (int m = 0; m < 2; ++m)
#pragma unroll
                for (int n = 0; n < 4; ++n)
#pragma unroll
                    for (int k2 = 0; k2 < 4; ++k2)
                        acc[m][n] = __builtin_amdgcn_mfma_f32_16x16x32_bf16(
                            a[m][4 + k2], b[n][k2], acc[m][n], 0, 0, 0);
            __builtin_amdgcn_s_setprio(0);
        }
        // ---- tile done: masked fold + rare pair extraction ----
#pragma unroll
        for (int m = 0; m < 2; ++m)
#pragma unroll
            for (int r = 0; r < 4; ++r) {
                int rl = rlab[m][r];
                float v = rmax[m][r];
                int hb = 0;
#pragma unroll
                for (int n = 0; n < 4; ++n) {
                    if (clab[n] != rl) v = fmaxf(v, acc[m][n][r]);
                    else hb |= 1 << n;
                }
                rmax[m][r] = v;
                if (hb) {                                // rare: same-label hit(s)
                    int grow_ = i0 + wr * 32 + m * 16 + kgrp * 4 + r;
#pragma unroll
                    for (int n = 0; n < 4; ++n)
                        if ((hb >> n) & 1) {
                            int gcol = cb + n * 16 + arow;
                            if (gcol > grow_) {
                                unsigned slot = atomicAdd(pcnt, 1u);
                                if (slot < PCAP)
                                    prec[slot] = make_uint2(
                                        (unsigned)grow_,
                                        __builtin_bit_cast(unsigned, acc[m][n][r]));
                            }
                        }
                }
            }
#pragma unroll
        for (int m = 0; m < 2; ++m)
#pragma unroll
            for (int n = 0; n < 4; ++n) acc[m][n] = (f32x4){0.f, 0.f, 0.f, 0.f};
#pragma unroll
        for (int n = 0; n < 4; ++n) clab[n] = nlab[n];
        cb += 128;
    }

    // Reduce over 16 col-lanes, combine wc pair via LDS, one atomic per row.
    __syncthreads();                                     // tile reads done
    float* smax = (float*)Bl;                            // [2][128] in buf0 (dead)
#pragma unroll
    for (int m = 0; m < 2; ++m)
#pragma unroll
        for (int r = 0; r < 4; ++r) {
            float v = rmax[m][r];
#pragma unroll
            for (int msk = 1; msk < 16; msk <<= 1) v = fmaxf(v, __shfl_xor(v, msk));
            if (arow == 0) smax[wc * 128 + wr * 32 + m * 16 + kgrp * 4 + r] = v;
        }
    __syncthreads();
    if (tid < 128) {
        float v = fmaxf(smax[tid], smax[128 + tid]);
        if (v > -1e29f) atomicMax(amax + i0 + tid, encf(v));
    }
}

// K3: finalize pair records: loss = relu(1 - dot - dmin[row] + margin)
__global__ __launch_bounds__(256) void k_pairfin(const uint2* __restrict__ prec,
                                                 const unsigned* __restrict__ pcnt,
                                                 const unsigned* __restrict__ amax,
                                                 float* __restrict__ pbl,
                                                 int* __restrict__ pbc) {
    __shared__ float sl[256];
    __shared__ int   sc[256];
    unsigned nrec = *pcnt;
    if (nrec > PCAP) nrec = PCAP;
    int tid = threadIdx.x;
    float ls = 0.f;
    int cn = 0;
    for (unsigned i = blockIdx.x * 256 + tid; i < nrec; i += 64 * 256) {
        uint2 rec = prec[i];
        unsigned e = amax[rec.x];
        if (e != 0u) {                                   // has_neg(anchor)
            float dmin = 1.0f - decf(e);
            float dot  = __builtin_bit_cast(float, rec.y);
            ls += fmaxf(1.0f - dot - dmin + MARGIN, 0.0f);
            cn += 1;
        }
    }
    sl[tid] = ls; sc[tid] = cn;
    __syncthreads();
    for (int st = 128; st > 0; st >>= 1) {
        if (tid < st) { sl[tid] += sl[tid + st]; sc[tid] += sc[tid + st]; }
        __syncthreads();
    }
    if (tid == 0) { pbl[blockIdx.x] = sl[0]; pbc[blockIdx.x] = sc[0]; }
}

// K4: final reduce over 64 partials -> out[0]=loss, out[1]=count
__global__ __launch_bounds__(64) void k_final(const float* __restrict__ pbl,
                                              const int* __restrict__ pbc,
                                              float* __restrict__ out) {
    int lane = threadIdx.x;
    float s = pbl[lane];
    int   c = pbc[lane];
#pragma unroll
    for (int m = 1; m < 64; m <<= 1) {
        s += __shfl_xor(s, m);
        c += __shfl_xor(c, m);
    }
    if (lane == 0) {
        out[0] = (c > 0) ? s / (float)c : 0.0f;
        out[1] = (float)c;
    }
}

extern "C" void kernel_launch(void* const* d_in, const int* in_sizes, int n_in,
                              void* d_out, int out_size, void* d_ws, size_t ws_size,
                              hipStream_t stream) {
    const float* emb  = (const float*)d_in[0];
    const int* labels = (const int*)d_in[1];
    float* out = (float*)d_out;

    char* ws = (char*)d_ws;
    unsigned short* xnb = (unsigned short*)ws;                            // 4 MB
    unsigned* amax = (unsigned*)(ws + (size_t)4 * 1024 * 1024);           // 32 KB
    unsigned* pcnt = (unsigned*)(ws + (size_t)4 * 1024 * 1024 + 32768);   // 4 B (padded)
    float*    pbl  = (float*)   (ws + (size_t)4 * 1024 * 1024 + 33024);   // 256 B
    int*      pbc  = (int*)     (ws + (size_t)4 * 1024 * 1024 + 33280);   // 256 B
    uint2*    prec = (uint2*)   (ws + (size_t)4 * 1024 * 1024 + 33792);   // 1 MB

    k_norm<<<NROWS / 4, 256, 0, stream>>>(emb, xnb, amax, pcnt);
    dim3 g2(NROWS / 128, NCLS / 64);   // 64 strips x 8 chunks
    k_maxneg<<<g2, 512, 65536, stream>>>(xnb, labels, amax, pcnt, prec);
    k_pairfin<<<64, 256, 0, stream>>>(prec, pcnt, amax, pbl, pbc);
    k_final<<<1, 64, 0, stream>>>(pbl, pbc, out);
}

// Round 7
// 180.100 us; speedup vs baseline: 4.0964x; 4.0579x over previous
//
#include <hip/hip_runtime.h>
#include <hip/hip_bf16.h>

#define NROWS 8192
#define DEMB 256
#define MARGIN 0.2f
#define NCLS 512
#define TPC 8                    // B tiles (128 cols) per chunk
#define PCAP 131072              // global pair-record capacity (expected ~65k)
#define BCAP 512                 // per-block LDS record capacity (expected ~128)

typedef __attribute__((ext_vector_type(4))) float f32x4;
typedef __attribute__((ext_vector_type(8))) short bf16x8;

static __device__ __forceinline__ unsigned short f2b(float f) {
    unsigned u = __builtin_bit_cast(unsigned, f);
    u += 0x7fffu + ((u >> 16) & 1u);           // RNE round to bf16
    return (unsigned short)(u >> 16);
}
static __device__ __forceinline__ float b2f(unsigned short b) {
    unsigned u = ((unsigned)b) << 16;
    return __builtin_bit_cast(float, u);
}
// order-preserving f32 -> u32 encode (max-compatible; finite values never encode to 0)
static __device__ __forceinline__ unsigned encf(float f) {
    unsigned u = __builtin_bit_cast(unsigned, f);
    return (u & 0x80000000u) ? ~u : (u | 0x80000000u);
}
static __device__ __forceinline__ float decf(unsigned e) {
    unsigned u = (e & 0x80000000u) ? (e ^ 0x80000000u) : ~e;
    return __builtin_bit_cast(float, u);
}
static __device__ __forceinline__ void gload16(const void* g, void* l) {
    __builtin_amdgcn_global_load_lds(
        (const __attribute__((address_space(1))) unsigned int*)g,
        (__attribute__((address_space(3))) unsigned int*)l, 16, 0, 0);
}

// K1: row-L2-normalize fp32 -> bf16; also zero amax + pair counter.
__global__ __launch_bounds__(256) void k_norm(const float* __restrict__ x,
                                              unsigned short* __restrict__ xnb,
                                              unsigned* __restrict__ amax,
                                              unsigned* __restrict__ pcnt) {
    int gid = blockIdx.x * blockDim.x + threadIdx.x;
    if (gid < NROWS) amax[gid] = 0u;
    if (gid == 0) *pcnt = 0u;
    int row  = gid >> 6;
    int lane = threadIdx.x & 63;
    const float4* p = reinterpret_cast<const float4*>(x + (size_t)row * DEMB) + lane;
    float4 v = *p;
    float s = v.x * v.x + v.y * v.y + v.z * v.z + v.w * v.w;
#pragma unroll
    for (int m = 1; m < 64; m <<= 1) s += __shfl_xor(s, m);
    float inv = 1.0f / fmaxf(sqrtf(s), 1e-8f);
    ushort4 o;
    o.x = f2b(v.x * inv); o.y = f2b(v.y * inv);
    o.z = f2b(v.z * inv); o.w = f2b(v.w * inv);
    *(reinterpret_cast<ushort4*>(xnb + (size_t)row * DEMB) + lane) = o;
}

// K2: strip-streaming MFMA row-max + positive-pair extraction.
// Grid (64 strips, 8 chunks), 512 threads. A-strip in registers; B streamed
// via dbuf LDS pipeline, 2 explicit half-K steps per tile. XOR-swizzled LDS.
// Pair hits buffered in LDS (block-local ds_add slot alloc); ONE global
// atomicAdd per block reserves a prec range at the end (bulk copy out).
__global__ __launch_bounds__(512, 2) void k_maxneg(const unsigned short* __restrict__ xnb,
                                                   const int* __restrict__ labels,
                                                   unsigned* __restrict__ amax,
                                                   unsigned* __restrict__ pcnt,
                                                   uint2* __restrict__ prec) {
    extern __shared__ char lds[];
    unsigned short* Bl = (unsigned short*)lds;   // dbuf: 2 x 32KB
    const char* BlC = (const char*)Bl;
    __shared__ uint2 hrec[BCAP];                 // 4KB pair-hit buffer
    __shared__ unsigned hcnt, hbase;

    int tid  = threadIdx.x;
    int wid  = tid >> 6, lane = tid & 63;
    int wr   = wid >> 1, wc = wid & 1;           // 4 row-subwaves x 2 col-subwaves
    int arow = lane & 15, kgrp = lane >> 4;
    int sw   = arow << 4;

    if (tid == 0) hcnt = 0u;

    int i0 = blockIdx.x * 128;
    int j0 = blockIdx.y * (TPC * 128);

    // Hoist A fragments: row = i0 + wr*32 + m*16 + arow, k = kk*32 + kgrp*8
    bf16x8 a[2][8];
    const unsigned short* ap0 = xnb + (size_t)(i0 + wr * 32 + arow) * DEMB + kgrp * 8;
#pragma unroll
    for (int m = 0; m < 2; ++m)
#pragma unroll
        for (int kk = 0; kk < 8; ++kk)
            a[m][kk] = *(const bf16x8*)(ap0 + m * 16 * DEMB + kk * 32);

    int rlab[2][4];
#pragma unroll
    for (int m = 0; m < 2; ++m)
#pragma unroll
        for (int r = 0; r < 4; ++r)
            rlab[m][r] = labels[i0 + wr * 32 + m * 16 + kgrp * 4 + r];

    // static swizzled ds_read offsets (n-stride 4096 added as literal)
    int rcb[4];
#pragma unroll
    for (int k2 = 0; k2 < 4; ++k2)
        rcb[k2] = (wc * 64 + arow) * 256 + ((k2 * 64 + kgrp * 16) ^ sw);

    float rmax[2][4] = {{-1e30f, -1e30f, -1e30f, -1e30f},
                        {-1e30f, -1e30f, -1e30f, -1e30f}};
    f32x4 acc[2][4] = {};

    // stage B half-tile: tile t, k-half h -> 128 rows x 128 k-cols = 32KB
    auto stage = [&](int buf, int t, int h) {
#pragma unroll
        for (int is = 0; is < 4; ++is) {
            int idx  = is * 512 + tid;                  // 16B chunk id 0..2047
            int row  = idx >> 4;                        // 16 chunks per 256B row
            int colb = (idx & 15) << 4;
            int scol = (colb ^ ((row & 15) << 4)) >> 1; // pre-swizzled elem col
            const unsigned short* src =
                xnb + (size_t)(j0 + t * 128 + row) * DEMB + h * 128 + scol;
            unsigned short* dst = Bl + buf * 16384 + is * 4096 + wid * 512;
            gload16(src, dst);
        }
    };

    int clab[4], nlab[4];
    stage(0, 0, 0);
#pragma unroll
    for (int n = 0; n < 4; ++n) clab[n] = labels[j0 + wc * 64 + n * 16 + arow];

    int cb = j0 + wc * 64;                               // column base of current tile

    for (int t = 0; t < TPC; ++t) {
        // ---- half 0: compute from buf0, prefetch half1 -> buf1 ----
        __syncthreads();                                 // buf0 ready (also hcnt init)
        stage(1, t, 1);
        if (t + 1 < TPC) {
#pragma unroll
            for (int n = 0; n < 4; ++n)
                nlab[n] = labels[j0 + (t + 1) * 128 + wc * 64 + n * 16 + arow];
        }
        {
            bf16x8 b[4][4];
#pragma unroll
            for (int n = 0; n < 4; ++n)
#pragma unroll
                for (int k2 = 0; k2 < 4; ++k2)
                    b[n][k2] = *(const bf16x8*)(BlC + n * 4096 + rcb[k2]);
#pragma unroll
            for (int m = 0; m < 2; ++m)
#pragma unroll
                for (int n = 0; n < 4; ++n)
#pragma unroll
                    for (int k2 = 0; k2 < 4; ++k2)
                        acc[m][n] = __builtin_amdgcn_mfma_f32_16x16x32_bf16(
                            a[m][k2], b[n][k2], acc[m][n], 0, 0, 0);
        }
        // ---- half 1: compute from buf1, prefetch next tile half0 -> buf0 ----
        __syncthreads();                                 // buf1 ready
        if (t + 1 < TPC) stage(0, t + 1, 0);
        {
            bf16x8 b[4][4];
#pragma unroll
            for (int n = 0; n < 4; ++n)
#pragma unroll
                for (int k2 = 0; k2 < 4; ++k2)
                    b[n][k2] = *(const bf16x8*)(BlC + 32768 + n * 4096 + rcb[k2]);
#pragma unroll
            for (int m = 0; m < 2; ++m)
#pragma unroll
                for (int n = 0; n < 4; ++n)
#pragma unroll
                    for (int k2 = 0; k2 < 4; ++k2)
                        acc[m][n] = __builtin_amdgcn_mfma_f32_16x16x32_bf16(
                            a[m][4 + k2], b[n][k2], acc[m][n], 0, 0, 0);
        }
        // ---- tile done: masked fold + rare pair extraction (LDS-buffered) ----
#pragma unroll
        for (int m = 0; m < 2; ++m)
#pragma unroll
            for (int r = 0; r < 4; ++r) {
                int rl = rlab[m][r];
                float v = rmax[m][r];
                int hb = 0;
#pragma unroll
                for (int n = 0; n < 4; ++n) {
                    if (clab[n] != rl) v = fmaxf(v, acc[m][n][r]);
                    else hb |= 1 << n;
                }
                rmax[m][r] = v;
                if (hb) {                                // rare: same-label hit(s)
                    int grow_ = i0 + wr * 32 + m * 16 + kgrp * 4 + r;
#pragma unroll
                    for (int n = 0; n < 4; ++n)
                        if ((hb >> n) & 1) {
                            int gcol = cb + n * 16 + arow;
                            if (gcol > grow_) {
                                unsigned slot = atomicAdd(&hcnt, 1u);  // LDS atomic
                                if (slot < BCAP)
                                    hrec[slot] = make_uint2(
                                        (unsigned)grow_,
                                        __builtin_bit_cast(unsigned, acc[m][n][r]));
                            }
                        }
                }
            }
#pragma unroll
        for (int m = 0; m < 2; ++m)
#pragma unroll
            for (int n = 0; n < 4; ++n) acc[m][n] = (f32x4){0.f, 0.f, 0.f, 0.f};
#pragma unroll
        for (int n = 0; n < 4; ++n) clab[n] = nlab[n];
        cb += 128;
    }

    // Reduce over 16 col-lanes, combine wc pair via LDS, one atomic per row.
    __syncthreads();                                     // tile reads + folds done
    float* smax = (float*)Bl;                            // [2][128] in buf0 (dead)
#pragma unroll
    for (int m = 0; m < 2; ++m)
#pragma unroll
        for (int r = 0; r < 4; ++r) {
            float v = rmax[m][r];
#pragma unroll
            for (int msk = 1; msk < 16; msk <<= 1) v = fmaxf(v, __shfl_xor(v, msk));
            if (arow == 0) smax[wc * 128 + wr * 32 + m * 16 + kgrp * 4 + r] = v;
        }
    __syncthreads();
    if (tid < 128) {
        float v = fmaxf(smax[tid], smax[128 + tid]);
        if (v > -1e29f) atomicMax(amax + i0 + tid, encf(v));
    }
    // Reserve contiguous prec range with ONE global atomic; bulk copy records.
    if (tid == 0) {
        unsigned nh = (hcnt < BCAP) ? hcnt : BCAP;
        hbase = atomicAdd(pcnt, nh);
    }
    __syncthreads();
    unsigned nh = (hcnt < BCAP) ? hcnt : BCAP;
    for (unsigned i = tid; i < nh; i += 512)
        if (hbase + i < PCAP) prec[hbase + i] = hrec[i];
}

// K3: finalize pair records: loss = relu(1 - dot - dmin[row] + margin)
__global__ __launch_bounds__(256) void k_pairfin(const uint2* __restrict__ prec,
                                                 const unsigned* __restrict__ pcnt,
                                                 const unsigned* __restrict__ amax,
                                                 float* __restrict__ pbl,
                                                 int* __restrict__ pbc) {
    __shared__ float sl[256];
    __shared__ int   sc[256];
    unsigned nrec = *pcnt;
    if (nrec > PCAP) nrec = PCAP;
    int tid = threadIdx.x;
    float ls = 0.f;
    int cn = 0;
    for (unsigned i = blockIdx.x * 256 + tid; i < nrec; i += 64 * 256) {
        uint2 rec = prec[i];
        unsigned e = amax[rec.x];
        if (e != 0u) {                                   // has_neg(anchor)
            float dmin = 1.0f - decf(e);
            float dot  = __builtin_bit_cast(float, rec.y);
            ls += fmaxf(1.0f - dot - dmin + MARGIN, 0.0f);
            cn += 1;
        }
    }
    sl[tid] = ls; sc[tid] = cn;
    __syncthreads();
    for (int st = 128; st > 0; st >>= 1) {
        if (tid < st) { sl[tid] += sl[tid + st]; sc[tid] += sc[tid + st]; }
        __syncthreads();
    }
    if (tid == 0) { pbl[blockIdx.x] = sl[0]; pbc[blockIdx.x] = sc[0]; }
}

// K4: final reduce over 64 partials -> out[0]=loss, out[1]=count
__global__ __launch_bounds__(64) void k_final(const float* __restrict__ pbl,
                                              const int* __restrict__ pbc,
                                              float* __restrict__ out) {
    int lane = threadIdx.x;
    float s = pbl[lane];
    int   c = pbc[lane];
#pragma unroll
    for (int m = 1; m < 64; m <<= 1) {
        s += __shfl_xor(s, m);
        c += __shfl_xor(c, m);
    }
    if (lane == 0) {
        out[0] = (c > 0) ? s / (float)c : 0.0f;
        out[1] = (float)c;
    }
}

extern "C" void kernel_launch(void* const* d_in, const int* in_sizes, int n_in,
                              void* d_out, int out_size, void* d_ws, size_t ws_size,
                              hipStream_t stream) {
    const float* emb  = (const float*)d_in[0];
    const int* labels = (const int*)d_in[1];
    float* out = (float*)d_out;

    char* ws = (char*)d_ws;
    unsigned short* xnb = (unsigned short*)ws;                            // 4 MB
    unsigned* amax = (unsigned*)(ws + (size_t)4 * 1024 * 1024);           // 32 KB
    unsigned* pcnt = (unsigned*)(ws + (size_t)4 * 1024 * 1024 + 32768);   // 4 B (padded)
    float*    pbl  = (float*)   (ws + (size_t)4 * 1024 * 1024 + 33024);   // 256 B
    int*      pbc  = (int*)     (ws + (size_t)4 * 1024 * 1024 + 33280);   // 256 B
    uint2*    prec = (uint2*)   (ws + (size_t)4 * 1024 * 1024 + 33792);   // 1 MB

    k_norm<<<NROWS / 4, 256, 0, stream>>>(emb, xnb, amax, pcnt);
    dim3 g2(NROWS / 128, NCLS / 64);   // 64 strips x 8 chunks
    k_maxneg<<<g2, 512, 65536, stream>>>(xnb, labels, amax, pcnt, prec);
    k_pairfin<<<64, 256, 0, stream>>>(prec, pcnt, amax, pbl, pbc);
    k_final<<<1, 64, 0, stream>>>(pbl, pbc, out);
}

// Round 8
// 80.129 us; speedup vs baseline: 9.2071x; 2.2476x over previous
//
#include <hip/hip_runtime.h>
#include <hip/hip_bf16.h>

#define NROWS 8192
#define DEMB 256
#define MARGIN 0.2f
#define NCLS 512
#define TPC 8                    // B tiles (128 cols) per chunk
#define NSTEP 16                 // 8 tiles * 2 half-K steps (BK=128)
#define MCAP 64                  // max class size (mean 16, 12 sigma)
#define SROW 264                 // padded LDS row stride (ushorts) for k_cpairs2

typedef __attribute__((ext_vector_type(4))) float f32x4;
typedef __attribute__((ext_vector_type(8))) short bf16x8;

static __device__ __forceinline__ unsigned short f2b(float f) {
    unsigned u = __builtin_bit_cast(unsigned, f);
    u += 0x7fffu + ((u >> 16) & 1u);           // RNE round to bf16
    return (unsigned short)(u >> 16);
}
static __device__ __forceinline__ float b2f(unsigned short b) {
    unsigned u = ((unsigned)b) << 16;
    return __builtin_bit_cast(float, u);
}
// order-preserving f32 -> u32 encode (max-compatible; finite values never encode to 0)
static __device__ __forceinline__ unsigned encf(float f) {
    unsigned u = __builtin_bit_cast(unsigned, f);
    return (u & 0x80000000u) ? ~u : (u | 0x80000000u);
}
static __device__ __forceinline__ float decf(unsigned e) {
    unsigned u = (e & 0x80000000u) ? (e ^ 0x80000000u) : ~e;
    return __builtin_bit_cast(float, u);
}
static __device__ __forceinline__ void gload16(const void* g, void* l) {
    __builtin_amdgcn_global_load_lds(
        (const __attribute__((address_space(1))) unsigned int*)g,
        (__attribute__((address_space(3))) unsigned int*)l, 16, 0, 0);
}

// K1: row-L2-normalize fp32 -> bf16; zero amax + class counters.
__global__ __launch_bounds__(256) void k_norm(const float* __restrict__ x,
                                              unsigned short* __restrict__ xnb,
                                              unsigned* __restrict__ amax,
                                              int* __restrict__ bcnt) {
    int gid = blockIdx.x * blockDim.x + threadIdx.x;
    if (gid < NROWS) amax[gid] = 0u;
    if (gid < NCLS) bcnt[gid] = 0;
    int row  = gid >> 6;
    int lane = threadIdx.x & 63;
    const float4* p = reinterpret_cast<const float4*>(x + (size_t)row * DEMB) + lane;
    float4 v = *p;
    float s = v.x * v.x + v.y * v.y + v.z * v.z + v.w * v.w;
#pragma unroll
    for (int m = 1; m < 64; m <<= 1) s += __shfl_xor(s, m);
    float inv = 1.0f / fmaxf(sqrtf(s), 1e-8f);
    ushort4 o;
    o.x = f2b(v.x * inv); o.y = f2b(v.y * inv);
    o.z = f2b(v.z * inv); o.w = f2b(v.w * inv);
    *(reinterpret_cast<ushort4*>(xnb + (size_t)row * DEMB) + lane) = o;
}

// K2: bucket rows by class. Order within a class is nondeterministic, but the
// pair SET derived from it is order-insensitive (anchor = min global index).
__global__ __launch_bounds__(256) void k_bucket(const int* __restrict__ labels,
                                                int* __restrict__ bcnt,
                                                int* __restrict__ mem) {
    int i = blockIdx.x * 256 + threadIdx.x;
    if (i < NROWS) {
        int l = labels[i];
        int slot = atomicAdd(&bcnt[l], 1);
        if (slot < MCAP) mem[l * MCAP + slot] = i;
    }
}

// K3: strip-streaming MFMA row-max (VERBATIM round-3 structure: 47.4us proven).
// Grid (64 strips, 8 chunks), 512 threads. A-strip fragments in registers;
// B streamed through 16-step double-buffered LDS pipeline (XOR-swizzled).
// Row-max accumulated in registers; one atomicMax set per block at the end.
__global__ __launch_bounds__(512, 2) void k_maxneg(const unsigned short* __restrict__ xnb,
                                                   const int* __restrict__ labels,
                                                   unsigned* __restrict__ amax) {
    extern __shared__ char lds[];
    unsigned short* Bl = (unsigned short*)lds;   // dbuf: 2 x 32KB

    int tid  = threadIdx.x;
    int wid  = tid >> 6, lane = tid & 63;
    int wr   = wid >> 1, wc = wid & 1;           // 4 row-subwaves x 2 col-subwaves
    int arow = lane & 15, kgrp = lane >> 4;

    int i0 = blockIdx.x * 128;
    int j0 = blockIdx.y * (TPC * 128);

    // Hoist A fragments: row = i0 + wr*32 + m*16 + arow, k = kk*32 + kgrp*8
    bf16x8 a[2][8];
    const unsigned short* ap0 = xnb + (size_t)(i0 + wr * 32 + arow) * DEMB + kgrp * 8;
#pragma unroll
    for (int m = 0; m < 2; ++m)
#pragma unroll
        for (int kk = 0; kk < 8; ++kk)
            a[m][kk] = *(const bf16x8*)(ap0 + m * 16 * DEMB + kk * 32);

    int rlab[2][4];
#pragma unroll
    for (int m = 0; m < 2; ++m)
#pragma unroll
        for (int r = 0; r < 4; ++r)
            rlab[m][r] = labels[i0 + wr * 32 + m * 16 + kgrp * 4 + r];

    float rmax[2][4] = {{-1e30f, -1e30f, -1e30f, -1e30f},
                        {-1e30f, -1e30f, -1e30f, -1e30f}};
    f32x4 acc[2][4] = {};

    // stage B half-tile: tile t, k-half h -> 128 rows x 128 k-cols = 32KB
    auto stage = [&](int buf, int t, int h) {
#pragma unroll
        for (int is = 0; is < 4; ++is) {
            int idx  = is * 512 + tid;                  // 16B chunk id 0..2047
            int row  = idx >> 4;                        // 16 chunks per 256B row
            int colb = (idx & 15) << 4;
            int scol = (colb ^ ((row & 15) << 4)) >> 1; // pre-swizzled elem col
            const unsigned short* src =
                xnb + (size_t)(j0 + t * 128 + row) * DEMB + h * 128 + scol;
            unsigned short* dst = Bl + buf * 16384 + is * 4096 + wid * 512;
            gload16(src, dst);
        }
    };

    int clab[4], nlab[4];
    stage(0, 0, 0);
#pragma unroll
    for (int n = 0; n < 4; ++n) clab[n] = labels[j0 + wc * 64 + n * 16 + arow];

    int sw = arow << 4;
    for (int s = 0; s < NSTEP; ++s) {
        __syncthreads();                                 // buf[s&1] ready
        if (s + 1 < NSTEP) stage((s + 1) & 1, (s + 1) >> 1, (s + 1) & 1);
        int tile = s >> 1, h = s & 1;
        if (h == 0 && tile + 1 < TPC) {
#pragma unroll
            for (int n = 0; n < 4; ++n)
                nlab[n] = labels[j0 + (tile + 1) * 128 + wc * 64 + n * 16 + arow];
        }
        const char* Bt = (const char*)(Bl + (s & 1) * 16384);
        bf16x8 b[4][4];
#pragma unroll
        for (int n = 0; n < 4; ++n) {
            int rb = (wc * 64 + n * 16 + arow) * 256;
#pragma unroll
            for (int ksl = 0; ksl < 4; ++ksl)
                b[n][ksl] = *(const bf16x8*)(Bt + rb + ((ksl * 64 + kgrp * 16) ^ sw));
        }
#pragma unroll
        for (int m = 0; m < 2; ++m)
#pragma unroll
            for (int n = 0; n < 4; ++n)
#pragma unroll
                for (int ksl = 0; ksl < 4; ++ksl)
                    acc[m][n] = __builtin_amdgcn_mfma_f32_16x16x32_bf16(
                        a[m][h * 4 + ksl], b[n][ksl], acc[m][n], 0, 0, 0);
        if (h == 1) {                                    // tile done: masked fold
#pragma unroll
            for (int m = 0; m < 2; ++m)
#pragma unroll
                for (int r = 0; r < 4; ++r) {
                    float v = rmax[m][r];
                    int rl = rlab[m][r];
#pragma unroll
                    for (int n = 0; n < 4; ++n)
                        if (clab[n] != rl) v = fmaxf(v, acc[m][n][r]);
                    rmax[m][r] = v;
                }
#pragma unroll
            for (int m = 0; m < 2; ++m)
#pragma unroll
                for (int n = 0; n < 4; ++n) acc[m][n] = (f32x4){0.f, 0.f, 0.f, 0.f};
#pragma unroll
            for (int n = 0; n < 4; ++n) clab[n] = nlab[n];
        }
    }

    // Reduce over 16 col-lanes, combine wc pair via LDS, one atomic per row.
    float* smax = (float*)Bl;                            // [2][128] in buf0 (dead)
#pragma unroll
    for (int m = 0; m < 2; ++m)
#pragma unroll
        for (int r = 0; r < 4; ++r) {
            float v = rmax[m][r];
#pragma unroll
            for (int msk = 1; msk < 16; msk <<= 1) v = fmaxf(v, __shfl_xor(v, msk));
            if (arow == 0) smax[wc * 128 + wr * 32 + m * 16 + kgrp * 4 + r] = v;
        }
    __syncthreads();
    if (tid < 128) {
        float v = fmaxf(smax[tid], smax[128 + tid]);
        if (v > -1e29f) atomicMax(amax + i0 + tid, encf(v));
    }
}

// K4: per-class pair losses from bucketed member lists. One block per class.
__global__ __launch_bounds__(256) void k_cpairs2(const unsigned short* __restrict__ xnb,
                                                 const unsigned* __restrict__ amax,
                                                 const int* __restrict__ bcnt,
                                                 const int* __restrict__ mem,
                                                 float* __restrict__ closs,
                                                 int* __restrict__ ccnt) {
    __shared__ unsigned short srows[MCAP * SROW];        // ~33.8 KB, padded stride
    __shared__ int mlist[MCAP];
    __shared__ float sdm[MCAP];
    __shared__ unsigned char shn[MCAP];
    __shared__ float slloss[16];
    __shared__ int slcnt[16];

    int c   = blockIdx.x;
    int tid = threadIdx.x;
    int nc  = bcnt[c];
    if (nc > MCAP) nc = MCAP;

    if (tid < nc) {
        int gi = mem[c * MCAP + tid];
        mlist[tid] = gi;
        unsigned e = amax[gi];
        shn[tid] = (e != 0u);
        sdm[tid] = 1.0f - decf(e);
    }
    __syncthreads();
    // gather rows (16B chunks)
    int nch = nc * 32;
    for (int ch = tid; ch < nch; ch += 256) {
        int r = ch >> 5, cc = ch & 31;
        *(bf16x8*)(srows + r * SROW + cc * 8) =
            *(const bf16x8*)(xnb + (size_t)mlist[r] * DEMB + cc * 8);
    }
    __syncthreads();

    // pair dots, 16-lane groups (4 pairs in flight per wave)
    int slot = tid >> 4, gl = tid & 15;
    int npairs = nc * (nc - 1) / 2;
    float gloss = 0.f;
    int gcnt = 0;
    for (int p = slot; p < npairs; p += 16) {
        int i = 0, rem = p;
        while (rem >= nc - 1 - i) { rem -= nc - 1 - i; ++i; }
        int j = i + 1 + rem;
        bf16x8 a0 = *(const bf16x8*)(srows + i * SROW + gl * 16);
        bf16x8 a1 = *(const bf16x8*)(srows + i * SROW + gl * 16 + 8);
        bf16x8 b0 = *(const bf16x8*)(srows + j * SROW + gl * 16);
        bf16x8 b1 = *(const bf16x8*)(srows + j * SROW + gl * 16 + 8);
        float dot = 0.f;
#pragma unroll
        for (int e = 0; e < 8; ++e) {
            dot += b2f((unsigned short)a0[e]) * b2f((unsigned short)b0[e]);
            dot += b2f((unsigned short)a1[e]) * b2f((unsigned short)b1[e]);
        }
#pragma unroll
        for (int msk = 1; msk < 16; msk <<= 1) dot += __shfl_xor(dot, msk);
        if (gl == 0) {
            int ai = (mlist[i] < mlist[j]) ? i : j;      // anchor = min global idx
            if (shn[ai]) {
                gloss += fmaxf(1.0f - dot - sdm[ai] + MARGIN, 0.0f);
                gcnt += 1;
            }
        }
    }
    if (gl == 0) { slloss[slot] = gloss; slcnt[slot] = gcnt; }
    __syncthreads();
    if (tid == 0) {
        float s = 0.f; int k = 0;
        for (int q = 0; q < 16; ++q) { s += slloss[q]; k += slcnt[q]; }
        closs[c] = s; ccnt[c] = k;
    }
}

// K5: final reduce over 512 classes -> out[0]=loss, out[1]=count
__global__ __launch_bounds__(256) void k_final(const float* __restrict__ closs,
                                               const int* __restrict__ ccnt,
                                               float* __restrict__ out) {
    __shared__ float sl[256];
    __shared__ int   sc[256];
    int tid = threadIdx.x;
    float s = closs[tid] + closs[tid + 256];
    int   k = ccnt[tid] + ccnt[tid + 256];
    sl[tid] = s; sc[tid] = k;
    __syncthreads();
    for (int st = 128; st > 0; st >>= 1) {
        if (tid < st) {
            sl[tid] += sl[tid + st];
            sc[tid] += sc[tid + st];
        }
        __syncthreads();
    }
    if (tid == 0) {
        out[0] = (sc[0] > 0) ? sl[0] / (float)sc[0] : 0.0f;
        out[1] = (float)sc[0];
    }
}

extern "C" void kernel_launch(void* const* d_in, const int* in_sizes, int n_in,
                              void* d_out, int out_size, void* d_ws, size_t ws_size,
                              hipStream_t stream) {
    const float* emb  = (const float*)d_in[0];
    const int* labels = (const int*)d_in[1];
    float* out = (float*)d_out;

    char* ws = (char*)d_ws;
    unsigned short* xnb = (unsigned short*)ws;                            // 4 MB
    unsigned* amax = (unsigned*)(ws + (size_t)4 * 1024 * 1024);           // 32 KB
    int* bcnt = (int*)(ws + (size_t)4 * 1024 * 1024 + 32768);             // 2 KB
    int* mem  = (int*)(ws + (size_t)4 * 1024 * 1024 + 34816);             // 128 KB
    float* closs = (float*)(ws + (size_t)4 * 1024 * 1024 + 34816 + 131072);
    int*   ccnt  = (int*)  (ws + (size_t)4 * 1024 * 1024 + 34816 + 131072 + 2048);

    k_norm<<<NROWS / 4, 256, 0, stream>>>(emb, xnb, amax, bcnt);
    k_bucket<<<NROWS / 256, 256, 0, stream>>>(labels, bcnt, mem);
    dim3 g2(NROWS / 128, NCLS / 64);   // 64 strips x 8 chunks
    k_maxneg<<<g2, 512, 65536, stream>>>(xnb, labels, amax);
    k_cpairs2<<<NCLS, 256, 0, stream>>>(xnb, amax, bcnt, mem, closs, ccnt);
    k_final<<<1, 256, 0, stream>>>(closs, ccnt, out);
}